// Round 14
// baseline (400.396 us; speedup 1.0000x reference)
//
#include <hip/hip_runtime.h>
#include <hip/hip_bf16.h>
#include <hip/hip_fp16.h>

#define N_NODES 100000
#define E_EDGES 1600000
#define IN_F    256
#define HEADS   4
#define DF      32
#define HD      128           // HEADS*DF
#define NEG_SLOPE 0.2f
#define SLOTS   64            // max in-degree capacity (Poisson(16): P(>64) ~ 1e-20)

typedef __attribute__((ext_vector_type(8))) _Float16 half8;
typedef __attribute__((ext_vector_type(2))) _Float16 h16x2;
typedef __attribute__((ext_vector_type(2))) float  f32x2;
typedef __attribute__((ext_vector_type(4))) float  f32x4;
typedef __attribute__((ext_vector_type(4))) _Float16 h16x4;

// ------ 0. convert+transpose weights to fp16 AND zero cnt (memset fused) ------
__global__ void k_prep(const float* __restrict__ wsrc,
                       const float* __restrict__ wdst,
                       _Float16* __restrict__ wsT,
                       _Float16* __restrict__ wdT,
                       int* __restrict__ cnt) {
    int i = blockIdx.x * 256 + threadIdx.x;
    for (int c = i; c < N_NODES; c += 128 * 256) cnt[c] = 0;
    if (i >= IN_F * HD) return;
    int k = i >> 7, n = i & 127;
    wsT[n * IN_F + k] = (_Float16)wsrc[i];
    wdT[n * IN_F + k] = (_Float16)wdst[i];
}

// ------ 1. dual GEMM, fp16, BM=128 tile (782 blocks), reg-staged K-pipeline ------
#define BM  128
#define NB_G ((N_NODES + BM - 1) / BM)   // 782
#define BK  32
#define LDK (BK + 8)     // fp16 stride 40 -> 80 B: 16B-aligned; 2-way bank alias = free
#define STG_LD (HD + 8)  // epilogue staging stride 136 fp16

__global__ void __launch_bounds__(256)
k_gemm(const float* __restrict__ x,
       const _Float16* __restrict__ wsT,
       const _Float16* __restrict__ wdT,
       const float* __restrict__ bsv,
       const float* __restrict__ bdv,
       _Float16* __restrict__ el, _Float16* __restrict__ er) {
    __shared__ _Float16 lds[3 * 128 * LDK];   // 30.72 KB; reused by epilogue
    _Float16 (*xs)[LDK] = (_Float16 (*)[LDK])(lds);                 // 128 x-rows
    _Float16 (*ws)[LDK] = (_Float16 (*)[LDK])(lds + 128 * LDK);     // 128 n-rows
    _Float16 (*wd)[LDK] = (_Float16 (*)[LDK])(lds + 256 * LDK);

    int tid  = threadIdx.x;
    int wave = tid >> 6, lane = tid & 63;
    int quad = lane >> 4, l16 = lane & 15;
    int rhalf = wave & 1, chalf = wave >> 1;   // wave owns rows rhalf*64+0..63, cols chalf*64+0..63
    int row0 = blockIdx.x * BM;

    int xr0 = tid >> 3, xc0 = (tid & 7) * 4;   // x rows xr0 + 32i (i=0..3)
    int wn0 = tid >> 2, wc0 = (tid & 3) * 8;   // w rows wn0 + 64i (i=0..1)

    f32x4 accS[4][4], accD[4][4];              // 128 VGPR
#pragma unroll
    for (int a = 0; a < 4; ++a)
#pragma unroll
        for (int b = 0; b < 4; ++b) {
            accS[a][b] = (f32x4){0.f, 0.f, 0.f, 0.f};
            accD[a][b] = (f32x4){0.f, 0.f, 0.f, 0.f};
        }

    float4 xv[4];
    half8  wsv[2], wdv[2];

    // prologue: load kc=0
#pragma unroll
    for (int i = 0; i < 4; ++i) {
        int gr = row0 + xr0 + i * 32;
        xv[i] = (gr < N_NODES) ? *(const float4*)(x + (long)gr * IN_F + xc0)
                               : make_float4(0.f, 0.f, 0.f, 0.f);
    }
#pragma unroll
    for (int i = 0; i < 2; ++i) {
        int go = (wn0 + i * 64) * IN_F + wc0;
        wsv[i] = *(const half8*)(wsT + go);
        wdv[i] = *(const half8*)(wdT + go);
    }
#pragma unroll
    for (int i = 0; i < 4; ++i) {
        f32x4 fv = (f32x4){xv[i].x, xv[i].y, xv[i].z, xv[i].w};
        *(h16x4*)(&xs[xr0 + i * 32][xc0]) = __builtin_convertvector(fv, h16x4);
    }
#pragma unroll
    for (int i = 0; i < 2; ++i) {
        *(half8*)(&ws[wn0 + i * 64][wc0]) = wsv[i];
        *(half8*)(&wd[wn0 + i * 64][wc0]) = wdv[i];
    }

    for (int kc = 0; kc < IN_F / BK; ++kc) {
        __syncthreads();                       // LDS for kc ready
        if (kc < IN_F / BK - 1) {              // issue loads for kc+1 (hide under MFMA)
            int ko = (kc + 1) * BK;
#pragma unroll
            for (int i = 0; i < 4; ++i) {
                int gr = row0 + xr0 + i * 32;
                xv[i] = (gr < N_NODES) ? *(const float4*)(x + (long)gr * IN_F + ko + xc0)
                                       : make_float4(0.f, 0.f, 0.f, 0.f);
            }
#pragma unroll
            for (int i = 0; i < 2; ++i) {
                int go = (wn0 + i * 64) * IN_F + ko + wc0;
                wsv[i] = *(const half8*)(wsT + go);
                wdv[i] = *(const half8*)(wdT + go);
            }
        }

        int kb = quad * 8;
        half8 a[4];
#pragma unroll
        for (int rt = 0; rt < 4; ++rt)
            a[rt] = *(const half8*)(&xs[rhalf * 64 + rt * 16 + l16][kb]);
#pragma unroll
        for (int ct = 0; ct < 4; ++ct) {
            int n = chalf * 64 + ct * 16 + l16;
            half8 bs = *(const half8*)(&ws[n][kb]);
            half8 bd = *(const half8*)(&wd[n][kb]);
#pragma unroll
            for (int rt = 0; rt < 4; ++rt) {
                accS[rt][ct] = __builtin_amdgcn_mfma_f32_16x16x32_f16(a[rt], bs, accS[rt][ct], 0, 0, 0);
                accD[rt][ct] = __builtin_amdgcn_mfma_f32_16x16x32_f16(a[rt], bd, accD[rt][ct], 0, 0, 0);
            }
        }
        __syncthreads();                       // all reads of kc done
        if (kc < IN_F / BK - 1) {
#pragma unroll
            for (int i = 0; i < 4; ++i) {
                f32x4 fv = (f32x4){xv[i].x, xv[i].y, xv[i].z, xv[i].w};
                *(h16x4*)(&xs[xr0 + i * 32][xc0]) = __builtin_convertvector(fv, h16x4);
            }
#pragma unroll
            for (int i = 0; i < 2; ++i) {
                *(half8*)(&ws[wn0 + i * 64][wc0]) = wsv[i];
                *(half8*)(&wd[wn0 + i * 64][wc0]) = wdv[i];
            }
        }
    }

    // ---- epilogue: 4 staged passes (S/D x rowhalf) through 64x136 LDS ----
    _Float16 (*stg)[STG_LD] = (_Float16 (*)[STG_LD])lds;
    int orow = tid >> 2, ocol = (tid & 3) * 32;

#pragma unroll
    for (int p = 0; p < 2; ++p) {              // S -> el, row halves
        __syncthreads();
        if (rhalf == p) {
#pragma unroll
            for (int ct = 0; ct < 4; ++ct) {
                int gc = chalf * 64 + ct * 16 + l16;
                float bf = bsv[gc];
#pragma unroll
                for (int rt = 0; rt < 4; ++rt)
#pragma unroll
                    for (int r = 0; r < 4; ++r)
                        stg[rt * 16 + quad * 4 + r][gc] = (_Float16)(accS[rt][ct][r] + bf);
            }
        }
        __syncthreads();
        int ogr = row0 + p * 64 + orow;
        if (ogr < N_NODES) {
#pragma unroll
            for (int k = 0; k < 4; ++k)
                *(half8*)(el + (long)ogr * HD + ocol + k * 8) =
                    *(const half8*)(&stg[orow][ocol + k * 8]);
        }
    }
#pragma unroll
    for (int p = 0; p < 2; ++p) {              // D -> er, row halves
        __syncthreads();
        if (rhalf == p) {
#pragma unroll
            for (int ct = 0; ct < 4; ++ct) {
                int gc = chalf * 64 + ct * 16 + l16;
                float bf = bdv[gc];
#pragma unroll
                for (int rt = 0; rt < 4; ++rt)
#pragma unroll
                    for (int r = 0; r < 4; ++r)
                        stg[rt * 16 + quad * 4 + r][gc] = (_Float16)(accD[rt][ct][r] + bf);
            }
        }
        __syncthreads();
        int ogr = row0 + p * 64 + orow;
        if (ogr < N_NODES) {
#pragma unroll
            for (int k = 0; k < 4; ++k)
                *(half8*)(er + (long)ogr * HD + ocol + k * 8) =
                    *(const half8*)(&stg[orow][ocol + k * 8]);
        }
    }
}

// ------ 2. bucket build, SINGLE-PASS (A/B vs XCD-partitioned 8-pass) ------
// Each thread owns 8 contiguous edges; indices read ONCE (12.8 MB vs ~100 MB).
// 8 independent {atomicAdd -> scatter} chains per thread; 782 blocks.
#define BCHUNK 2048   // edges per block = 256 threads x 8
#define NB_B ((E_EDGES + BCHUNK - 1) / BCHUNK)   // 782

__global__ void __launch_bounds__(256)
k_build(const int* __restrict__ src, const int* __restrict__ dst,
        int* __restrict__ cnt, int2* __restrict__ epair) {
    long eb = (long)blockIdx.x * BCHUNK + threadIdx.x * 8;
    if (eb >= E_EDGES) return;

    if (eb + 8 <= E_EDGES) {
        int4 d0 = *(const int4*)(dst + eb);
        int4 d1 = *(const int4*)(dst + eb + 4);
        int4 s0 = *(const int4*)(src + eb);
        int4 s1 = *(const int4*)(src + eb + 4);
        int dv[8] = {d0.x, d0.y, d0.z, d0.w, d1.x, d1.y, d1.z, d1.w};
        int sv[8] = {s0.x, s0.y, s0.z, s0.w, s1.x, s1.y, s1.z, s1.w};
#pragma unroll
        for (int i = 0; i < 8; ++i) {
            int d = dv[i];
            int pos = atomicAdd(&cnt[d], 1);
            if (pos < SLOTS) epair[((long)d << 6) + pos] = make_int2(sv[i], (int)eb + i);
        }
    } else {
        for (int i = 0; eb + i < E_EDGES; ++i) {
            int d = dst[eb + i];
            int pos = atomicAdd(&cnt[d], 1);
            if (pos < SLOTS) epair[((long)d << 6) + pos] = make_int2(src[eb + i], (int)eb + i);
        }
    }
}

// ------ 3. fused per-node softmax + aggregate (round-9 measured-best config) ------
// 4 edges/iteration x 8 lanes/edge (16 features per lane); 8 nodes per 256-block.
// Score: packed fp16 add+leakyrelu + v_dot2_f32_f16; aggregate via packed f32 FMA.
__global__ void __launch_bounds__(256)
k_node(const int* __restrict__ cnt,
       const int2* __restrict__ epair,
       const _Float16* __restrict__ el, const _Float16* __restrict__ er,
       const float* __restrict__ attn,
       float* __restrict__ out0, float* __restrict__ out1) {
    __shared__ float pex[8][SLOTS][HEADS];   // 8 KB

    int nd = threadIdx.x >> 5;               // node-in-block (0-7)
    int d  = blockIdx.x * 8 + nd;
    int l  = threadIdx.x & 31;
    int g  = l >> 3;                         // edge slot within iteration (0-3)
    int r  = l & 7;                          // lane within edge (8 lanes x 16 feats)
    int hh = r >> 1;                         // head
    int qq = r & 1;                          // half of head (feature group of 16)

    const half8* erp = (const half8*)(er + (long)d * HD + r * 16);
    half8 rv0 = erp[0], rv1 = erp[1];
    h16x2 av2[8];
#pragma unroll
    for (int k = 0; k < 8; ++k) {
        av2[k][0] = (_Float16)attn[hh * DF + qq * 16 + 2 * k];
        av2[k][1] = (_Float16)attn[hh * DF + qq * 16 + 2 * k + 1];
    }

    int deg = cnt[d];
    deg = deg < SLOTS ? deg : SLOTS;
    const int2* rowp = epair + ((long)d << 6);

    int2 epA = (l      < deg) ? rowp[l]      : make_int2(0, 0);
    int2 epB = (32 + l < deg) ? rowp[32 + l] : make_int2(0, 0);

    f32x2 acc2[8];
#pragma unroll
    for (int k = 0; k < 8; ++k) acc2[k] = (f32x2){0.f, 0.f};
    float den = 0.f;

    int nit = (deg + 3) >> 2;

    half8 pf0a, pf0b, pf1a, pf1b;
    {
        int s0 = __shfl(epA.x, g, 32);
        const half8* p0 = (const half8*)(el + (long)s0 * HD + r * 16);
        pf0a = p0[0]; pf0b = p0[1];
        int s1 = __shfl(epA.x, 4 + g, 32);
        const half8* p1 = (const half8*)(el + (long)s1 * HD + r * 16);
        pf1a = p1[0]; pf1b = p1[1];
    }

    const h16x2 hz = (h16x2){(_Float16)0.f, (_Float16)0.f};
    const _Float16 hs = (_Float16)NEG_SLOPE;

    for (int b = 0; b < nit * 4; b += 4) {
        half8 ev0 = pf0a, ev1 = pf0b;
        pf0a = pf1a; pf0b = pf1b;
        int nb = b + 8;
        int jj = nb + g; jj = jj < 63 ? jj : 63;
        int sN = (nb < 32) ? __shfl(epA.x, jj, 32) : __shfl(epB.x, jj - 32, 32);
        const half8* pn = (const half8*)(el + (long)sN * HD + r * 16);
        pf1a = pn[0]; pf1b = pn[1];

        int j = b + g;
        float p = 0.f;
#pragma unroll
        for (int k = 0; k < 8; ++k) {
            half8 eq = (k < 4) ? ev0 : ev1;
            half8 rq = (k < 4) ? rv0 : rv1;
            int e0 = (k & 3) * 2;
            h16x2 t   = (h16x2){ (_Float16)(eq[e0] + rq[e0]),
                                 (_Float16)(eq[e0 + 1] + rq[e0 + 1]) };
            h16x2 pos = __builtin_elementwise_max(t, hz);
            h16x2 neg = __builtin_elementwise_min(t, hz);
            h16x2 lr  = pos + neg * hs;
            p = __builtin_amdgcn_fdot2(lr, av2[k], p, false);
        }
        p += __shfl_xor(p, 1, 32);
        bool valid = j < deg;
        float ex = valid ? __expf(p) : 0.f;
        den += ex;
        f32x2 ex2 = (f32x2){ex, ex};
#pragma unroll
        for (int k = 0; k < 8; ++k) {
            half8 eq = (k < 4) ? ev0 : ev1;
            int e0 = (k & 3) * 2;
            f32x2 ev2 = (f32x2){(float)eq[e0], (float)eq[e0 + 1]};
            acc2[k] = acc2[k] + ex2 * ev2;    // v_pk_fma_f32
        }
        if (((l & 1) == 0) && valid) pex[nd][j][hh] = ex;
    }

    den += __shfl_xor(den, 8, 32);
    den += __shfl_xor(den, 16, 32);
    float rden = den > 0.f ? 1.0f / den : 0.f;

    float w = rden * 0.25f;
    float accf[16];
#pragma unroll
    for (int k = 0; k < 8; ++k) { accf[2 * k] = acc2[k][0]; accf[2 * k + 1] = acc2[k][1]; }
#pragma unroll
    for (int k = 0; k < 16; ++k) {
        float fa = accf[k] * w;
        fa += __shfl_xor(fa, 2, 32);
        fa += __shfl_xor(fa, 4, 32);
        fa += __shfl_xor(fa, 8, 32);
        fa += __shfl_xor(fa, 16, 32);
        accf[k] = fa;
    }
    if (l < 2) {
        float* o = out0 + (long)d * DF + l * 16;
#pragma unroll
        for (int k = 0; k < 4; ++k) {
            *(float4*)(o + k * 4) = make_float4(accf[k * 4], accf[k * 4 + 1],
                                                accf[k * 4 + 2], accf[k * 4 + 3]);
        }
    }

    __asm__ volatile("s_waitcnt lgkmcnt(0)" ::: "memory");

    float r0 = __shfl(rden, 0, 32);
    float r1 = __shfl(rden, 2, 32);
    float r2 = __shfl(rden, 4, 32);
    float r3 = __shfl(rden, 6, 32);

    if (l < deg) {
        float4 exv = *(const float4*)(&pex[nd][l][0]);
        out1[epA.y] = 0.25f * (exv.x * r0 + exv.y * r1 + exv.z * r2 + exv.w * r3);
    }
    if (32 + l < deg) {
        float4 exv = *(const float4*)(&pex[nd][32 + l][0]);
        out1[epB.y] = 0.25f * (exv.x * r0 + exv.y * r1 + exv.z * r2 + exv.w * r3);
    }
}

extern "C" void kernel_launch(void* const* d_in, const int* in_sizes, int n_in,
                              void* d_out, int out_size, void* d_ws, size_t ws_size,
                              hipStream_t stream) {
    const float* x     = (const float*)d_in[0];
    const float* w_src = (const float*)d_in[1];
    const float* b_src = (const float*)d_in[2];
    const float* w_dst = (const float*)d_in[3];
    const float* b_dst = (const float*)d_in[4];
    const float* attn  = (const float*)d_in[5];
    const int* src = (const int*)d_in[6];
    const int* dst = (const int*)d_in[7];

    char* ws = (char*)d_ws;
    _Float16* el    = (_Float16*)(ws + 0);          // N*128 fp16 = 25.6 MB
    _Float16* er    = (_Float16*)(ws + 25600000);   // N*128 fp16 = 25.6 MB
    int*      cnt   = (int*)(ws + 51200000);        // 400 KB
    int2*     epair = (int2*)(ws + 51600000);       // N*64*8 = 51.2 MB
    _Float16* wsT   = (_Float16*)(ws + 102800000);  // 64 KB
    _Float16* wdT   = (_Float16*)(ws + 102865536);  // 64 KB

    float* out0 = (float*)d_out;                // ft.mean: N*32 fp32
    float* out1 = out0 + N_NODES * DF;          // a.mean:  E fp32

    k_prep<<<128, 256, 0, stream>>>(w_src, w_dst, wsT, wdT, cnt);
    k_gemm<<<NB_G, 256, 0, stream>>>(x, wsT, wdT, b_src, b_dst, el, er);
    k_build<<<NB_B, 256, 0, stream>>>(src, dst, cnt, epair);
    k_node<<<N_NODES / 8, 256, 0, stream>>>(cnt, epair, el, er, attn, out0, out1);
}

// Round 16
// 348.959 us; speedup vs baseline: 1.1474x; 1.1474x over previous
//
#include <hip/hip_runtime.h>
#include <hip/hip_bf16.h>
#include <hip/hip_fp16.h>

#define N_NODES 100000
#define E_EDGES 1600000
#define IN_F    256
#define HEADS   4
#define DF      32
#define HD      128           // HEADS*DF
#define NEG_SLOPE 0.2f
#define SLOTS   64            // max in-degree capacity (Poisson(16): P(>64) ~ 1e-20)

#define XCDS 8
#define NODES_PER_XCD (N_NODES / XCDS)     // 12500
#define BUILD_SLICES 800
#define CHUNK (E_EDGES / BUILD_SLICES)     // 2000 = 250 threads x 8 edges exactly

typedef __attribute__((ext_vector_type(8))) _Float16 half8;
typedef __attribute__((ext_vector_type(2))) _Float16 h16x2;
typedef __attribute__((ext_vector_type(2))) float  f32x2;
typedef __attribute__((ext_vector_type(4))) float  f32x4;
typedef __attribute__((ext_vector_type(4))) _Float16 h16x4;

// ------ 0. convert+transpose weights to fp16 AND zero cnt (memset fused) ------
__global__ void k_prep(const float* __restrict__ wsrc,
                       const float* __restrict__ wdst,
                       _Float16* __restrict__ wsT,
                       _Float16* __restrict__ wdT,
                       int* __restrict__ cnt) {
    int i = blockIdx.x * 256 + threadIdx.x;
    for (int c = i; c < N_NODES; c += 128 * 256) cnt[c] = 0;
    if (i >= IN_F * HD) return;
    int k = i >> 7, n = i & 127;
    wsT[n * IN_F + k] = (_Float16)wsrc[i];
    wdT[n * IN_F + k] = (_Float16)wdst[i];
}

// ------ 1. dual GEMM, fp16, BM=128 tile (782 blocks), reg-staged K-pipeline ------
#define BM  128
#define NB_G ((N_NODES + BM - 1) / BM)   // 782
#define BK  32
#define LDK (BK + 8)     // fp16 stride 40 -> 80 B: 16B-aligned; 2-way bank alias = free
#define STG_LD (HD + 8)  // epilogue staging stride 136 fp16

__global__ void __launch_bounds__(256)
k_gemm(const float* __restrict__ x,
       const _Float16* __restrict__ wsT,
       const _Float16* __restrict__ wdT,
       const float* __restrict__ bsv,
       const float* __restrict__ bdv,
       _Float16* __restrict__ el, _Float16* __restrict__ er) {
    __shared__ _Float16 lds[3 * 128 * LDK];   // 30.72 KB; reused by epilogue
    _Float16 (*xs)[LDK] = (_Float16 (*)[LDK])(lds);                 // 128 x-rows
    _Float16 (*ws)[LDK] = (_Float16 (*)[LDK])(lds + 128 * LDK);     // 128 n-rows
    _Float16 (*wd)[LDK] = (_Float16 (*)[LDK])(lds + 256 * LDK);

    int tid  = threadIdx.x;
    int wave = tid >> 6, lane = tid & 63;
    int quad = lane >> 4, l16 = lane & 15;
    int rhalf = wave & 1, chalf = wave >> 1;   // wave owns rows rhalf*64+0..63, cols chalf*64+0..63
    int row0 = blockIdx.x * BM;

    int xr0 = tid >> 3, xc0 = (tid & 7) * 4;   // x rows xr0 + 32i (i=0..3)
    int wn0 = tid >> 2, wc0 = (tid & 3) * 8;   // w rows wn0 + 64i (i=0..1)

    f32x4 accS[4][4], accD[4][4];              // 128 VGPR
#pragma unroll
    for (int a = 0; a < 4; ++a)
#pragma unroll
        for (int b = 0; b < 4; ++b) {
            accS[a][b] = (f32x4){0.f, 0.f, 0.f, 0.f};
            accD[a][b] = (f32x4){0.f, 0.f, 0.f, 0.f};
        }

    float4 xv[4];
    half8  wsv[2], wdv[2];

    // prologue: load kc=0
#pragma unroll
    for (int i = 0; i < 4; ++i) {
        int gr = row0 + xr0 + i * 32;
        xv[i] = (gr < N_NODES) ? *(const float4*)(x + (long)gr * IN_F + xc0)
                               : make_float4(0.f, 0.f, 0.f, 0.f);
    }
#pragma unroll
    for (int i = 0; i < 2; ++i) {
        int go = (wn0 + i * 64) * IN_F + wc0;
        wsv[i] = *(const half8*)(wsT + go);
        wdv[i] = *(const half8*)(wdT + go);
    }
#pragma unroll
    for (int i = 0; i < 4; ++i) {
        f32x4 fv = (f32x4){xv[i].x, xv[i].y, xv[i].z, xv[i].w};
        *(h16x4*)(&xs[xr0 + i * 32][xc0]) = __builtin_convertvector(fv, h16x4);
    }
#pragma unroll
    for (int i = 0; i < 2; ++i) {
        *(half8*)(&ws[wn0 + i * 64][wc0]) = wsv[i];
        *(half8*)(&wd[wn0 + i * 64][wc0]) = wdv[i];
    }

    for (int kc = 0; kc < IN_F / BK; ++kc) {
        __syncthreads();                       // LDS for kc ready
        if (kc < IN_F / BK - 1) {              // issue loads for kc+1 (hide under MFMA)
            int ko = (kc + 1) * BK;
#pragma unroll
            for (int i = 0; i < 4; ++i) {
                int gr = row0 + xr0 + i * 32;
                xv[i] = (gr < N_NODES) ? *(const float4*)(x + (long)gr * IN_F + ko + xc0)
                                       : make_float4(0.f, 0.f, 0.f, 0.f);
            }
#pragma unroll
            for (int i = 0; i < 2; ++i) {
                int go = (wn0 + i * 64) * IN_F + ko + wc0;
                wsv[i] = *(const half8*)(wsT + go);
                wdv[i] = *(const half8*)(wdT + go);
            }
        }

        int kb = quad * 8;
        half8 a[4];
#pragma unroll
        for (int rt = 0; rt < 4; ++rt)
            a[rt] = *(const half8*)(&xs[rhalf * 64 + rt * 16 + l16][kb]);
#pragma unroll
        for (int ct = 0; ct < 4; ++ct) {
            int n = chalf * 64 + ct * 16 + l16;
            half8 bs = *(const half8*)(&ws[n][kb]);
            half8 bd = *(const half8*)(&wd[n][kb]);
#pragma unroll
            for (int rt = 0; rt < 4; ++rt) {
                accS[rt][ct] = __builtin_amdgcn_mfma_f32_16x16x32_f16(a[rt], bs, accS[rt][ct], 0, 0, 0);
                accD[rt][ct] = __builtin_amdgcn_mfma_f32_16x16x32_f16(a[rt], bd, accD[rt][ct], 0, 0, 0);
            }
        }
        __syncthreads();                       // all reads of kc done
        if (kc < IN_F / BK - 1) {
#pragma unroll
            for (int i = 0; i < 4; ++i) {
                f32x4 fv = (f32x4){xv[i].x, xv[i].y, xv[i].z, xv[i].w};
                *(h16x4*)(&xs[xr0 + i * 32][xc0]) = __builtin_convertvector(fv, h16x4);
            }
#pragma unroll
            for (int i = 0; i < 2; ++i) {
                *(half8*)(&ws[wn0 + i * 64][wc0]) = wsv[i];
                *(half8*)(&wd[wn0 + i * 64][wc0]) = wdv[i];
            }
        }
    }

    // ---- epilogue: 4 staged passes (S/D x rowhalf) through 64x136 LDS ----
    _Float16 (*stg)[STG_LD] = (_Float16 (*)[STG_LD])lds;
    int orow = tid >> 2, ocol = (tid & 3) * 32;

#pragma unroll
    for (int p = 0; p < 2; ++p) {              // S -> el, row halves
        __syncthreads();
        if (rhalf == p) {
#pragma unroll
            for (int ct = 0; ct < 4; ++ct) {
                int gc = chalf * 64 + ct * 16 + l16;
                float bf = bsv[gc];
#pragma unroll
                for (int rt = 0; rt < 4; ++rt)
#pragma unroll
                    for (int r = 0; r < 4; ++r)
                        stg[rt * 16 + quad * 4 + r][gc] = (_Float16)(accS[rt][ct][r] + bf);
            }
        }
        __syncthreads();
        int ogr = row0 + p * 64 + orow;
        if (ogr < N_NODES) {
#pragma unroll
            for (int k = 0; k < 4; ++k)
                *(half8*)(el + (long)ogr * HD + ocol + k * 8) =
                    *(const half8*)(&stg[orow][ocol + k * 8]);
        }
    }
#pragma unroll
    for (int p = 0; p < 2; ++p) {              // D -> er, row halves
        __syncthreads();
        if (rhalf == p) {
#pragma unroll
            for (int ct = 0; ct < 4; ++ct) {
                int gc = chalf * 64 + ct * 16 + l16;
                float bf = bdv[gc];
#pragma unroll
                for (int rt = 0; rt < 4; ++rt)
#pragma unroll
                    for (int r = 0; r < 4; ++r)
                        stg[rt * 16 + quad * 4 + r][gc] = (_Float16)(accD[rt][ct][r] + bf);
            }
        }
        __syncthreads();
        int ogr = row0 + p * 64 + orow;
        if (ogr < N_NODES) {
#pragma unroll
            for (int k = 0; k < 4; ++k)
                *(half8*)(er + (long)ogr * HD + ocol + k * 8) =
                    *(const half8*)(&stg[orow][ocol + k * 8]);
        }
    }
}

// ------ 2. bucket build, XCD-partitioned, int4-vectorized (measured best) ------
// 8-pass over edges by XCD residue: redundant index reads are L3-served; buys
// XCD-local epair/cnt lines (single-pass A/B: 135 µs vs this 76 µs, r14).
// Grid MUST be XCDS * BUILD_SLICES = 6400 (j = blockIdx>>3 covers 800 chunks).
__global__ void __launch_bounds__(256)
k_build(const int* __restrict__ src, const int* __restrict__ dst,
        int* __restrict__ cnt, int2* __restrict__ epair) {
    int x = blockIdx.x & 7;
    int j = blockIdx.x >> 3;
    int lo = x * NODES_PER_XCD;
    int hi = lo + NODES_PER_XCD;
    int e0 = j * CHUNK;
    int eb = e0 + threadIdx.x * 8;
    if (eb >= e0 + CHUNK) return;              // CHUNK=2000 -> threads 250..255 idle

    int4 d0 = *(const int4*)(dst + eb);
    int4 d1 = *(const int4*)(dst + eb + 4);
    int4 s0 = *(const int4*)(src + eb);
    int4 s1 = *(const int4*)(src + eb + 4);

    int dv[8] = {d0.x, d0.y, d0.z, d0.w, d1.x, d1.y, d1.z, d1.w};
    int sv[8] = {s0.x, s0.y, s0.z, s0.w, s1.x, s1.y, s1.z, s1.w};

#pragma unroll
    for (int i = 0; i < 8; ++i) {
        int d = dv[i];
        if (d >= lo && d < hi) {
            int pos = atomicAdd(&cnt[d], 1);
            if (pos < SLOTS) epair[((long)d << 6) + pos] = make_int2(sv[i], eb + i);
        }
    }
}

// ------ 3. fused per-node softmax + aggregate (round-9 measured-best config) ------
// 4 edges/iteration x 8 lanes/edge (16 features per lane); 8 nodes per 256-block.
// Score: packed fp16 add+leakyrelu + v_dot2_f32_f16; aggregate via packed f32 FMA.
__global__ void __launch_bounds__(256)
k_node(const int* __restrict__ cnt,
       const int2* __restrict__ epair,
       const _Float16* __restrict__ el, const _Float16* __restrict__ er,
       const float* __restrict__ attn,
       float* __restrict__ out0, float* __restrict__ out1) {
    __shared__ float pex[8][SLOTS][HEADS];   // 8 KB

    int nd = threadIdx.x >> 5;               // node-in-block (0-7)
    int d  = blockIdx.x * 8 + nd;
    int l  = threadIdx.x & 31;
    int g  = l >> 3;                         // edge slot within iteration (0-3)
    int r  = l & 7;                          // lane within edge (8 lanes x 16 feats)
    int hh = r >> 1;                         // head
    int qq = r & 1;                          // half of head (feature group of 16)

    const half8* erp = (const half8*)(er + (long)d * HD + r * 16);
    half8 rv0 = erp[0], rv1 = erp[1];
    h16x2 av2[8];
#pragma unroll
    for (int k = 0; k < 8; ++k) {
        av2[k][0] = (_Float16)attn[hh * DF + qq * 16 + 2 * k];
        av2[k][1] = (_Float16)attn[hh * DF + qq * 16 + 2 * k + 1];
    }

    int deg = cnt[d];
    deg = deg < SLOTS ? deg : SLOTS;
    const int2* rowp = epair + ((long)d << 6);

    int2 epA = (l      < deg) ? rowp[l]      : make_int2(0, 0);
    int2 epB = (32 + l < deg) ? rowp[32 + l] : make_int2(0, 0);

    f32x2 acc2[8];
#pragma unroll
    for (int k = 0; k < 8; ++k) acc2[k] = (f32x2){0.f, 0.f};
    float den = 0.f;

    int nit = (deg + 3) >> 2;

    half8 pf0a, pf0b, pf1a, pf1b;
    {
        int s0 = __shfl(epA.x, g, 32);
        const half8* p0 = (const half8*)(el + (long)s0 * HD + r * 16);
        pf0a = p0[0]; pf0b = p0[1];
        int s1 = __shfl(epA.x, 4 + g, 32);
        const half8* p1 = (const half8*)(el + (long)s1 * HD + r * 16);
        pf1a = p1[0]; pf1b = p1[1];
    }

    const h16x2 hz = (h16x2){(_Float16)0.f, (_Float16)0.f};
    const _Float16 hs = (_Float16)NEG_SLOPE;

    for (int b = 0; b < nit * 4; b += 4) {
        half8 ev0 = pf0a, ev1 = pf0b;
        pf0a = pf1a; pf0b = pf1b;
        int nb = b + 8;
        int jj = nb + g; jj = jj < 63 ? jj : 63;
        int sN = (nb < 32) ? __shfl(epA.x, jj, 32) : __shfl(epB.x, jj - 32, 32);
        const half8* pn = (const half8*)(el + (long)sN * HD + r * 16);
        pf1a = pn[0]; pf1b = pn[1];

        int j = b + g;
        float p = 0.f;
#pragma unroll
        for (int k = 0; k < 8; ++k) {
            half8 eq = (k < 4) ? ev0 : ev1;
            half8 rq = (k < 4) ? rv0 : rv1;
            int e0 = (k & 3) * 2;
            h16x2 t   = (h16x2){ (_Float16)(eq[e0] + rq[e0]),
                                 (_Float16)(eq[e0 + 1] + rq[e0 + 1]) };
            h16x2 pos = __builtin_elementwise_max(t, hz);
            h16x2 neg = __builtin_elementwise_min(t, hz);
            h16x2 lr  = pos + neg * hs;
            p = __builtin_amdgcn_fdot2(lr, av2[k], p, false);
        }
        p += __shfl_xor(p, 1, 32);
        bool valid = j < deg;
        float ex = valid ? __expf(p) : 0.f;
        den += ex;
        f32x2 ex2 = (f32x2){ex, ex};
#pragma unroll
        for (int k = 0; k < 8; ++k) {
            half8 eq = (k < 4) ? ev0 : ev1;
            int e0 = (k & 3) * 2;
            f32x2 ev2 = (f32x2){(float)eq[e0], (float)eq[e0 + 1]};
            acc2[k] = acc2[k] + ex2 * ev2;    // v_pk_fma_f32
        }
        if (((l & 1) == 0) && valid) pex[nd][j][hh] = ex;
    }

    den += __shfl_xor(den, 8, 32);
    den += __shfl_xor(den, 16, 32);
    float rden = den > 0.f ? 1.0f / den : 0.f;

    float w = rden * 0.25f;
    float accf[16];
#pragma unroll
    for (int k = 0; k < 8; ++k) { accf[2 * k] = acc2[k][0]; accf[2 * k + 1] = acc2[k][1]; }
#pragma unroll
    for (int k = 0; k < 16; ++k) {
        float fa = accf[k] * w;
        fa += __shfl_xor(fa, 2, 32);
        fa += __shfl_xor(fa, 4, 32);
        fa += __shfl_xor(fa, 8, 32);
        fa += __shfl_xor(fa, 16, 32);
        accf[k] = fa;
    }
    if (l < 2) {
        float* o = out0 + (long)d * DF + l * 16;
#pragma unroll
        for (int k = 0; k < 4; ++k) {
            *(float4*)(o + k * 4) = make_float4(accf[k * 4], accf[k * 4 + 1],
                                                accf[k * 4 + 2], accf[k * 4 + 3]);
        }
    }

    __asm__ volatile("s_waitcnt lgkmcnt(0)" ::: "memory");

    float r0 = __shfl(rden, 0, 32);
    float r1 = __shfl(rden, 2, 32);
    float r2 = __shfl(rden, 4, 32);
    float r3 = __shfl(rden, 6, 32);

    if (l < deg) {
        float4 exv = *(const float4*)(&pex[nd][l][0]);
        out1[epA.y] = 0.25f * (exv.x * r0 + exv.y * r1 + exv.z * r2 + exv.w * r3);
    }
    if (32 + l < deg) {
        float4 exv = *(const float4*)(&pex[nd][32 + l][0]);
        out1[epB.y] = 0.25f * (exv.x * r0 + exv.y * r1 + exv.z * r2 + exv.w * r3);
    }
}

extern "C" void kernel_launch(void* const* d_in, const int* in_sizes, int n_in,
                              void* d_out, int out_size, void* d_ws, size_t ws_size,
                              hipStream_t stream) {
    const float* x     = (const float*)d_in[0];
    const float* w_src = (const float*)d_in[1];
    const float* b_src = (const float*)d_in[2];
    const float* w_dst = (const float*)d_in[3];
    const float* b_dst = (const float*)d_in[4];
    const float* attn  = (const float*)d_in[5];
    const int* src = (const int*)d_in[6];
    const int* dst = (const int*)d_in[7];

    char* ws = (char*)d_ws;
    _Float16* el    = (_Float16*)(ws + 0);          // N*128 fp16 = 25.6 MB
    _Float16* er    = (_Float16*)(ws + 25600000);   // N*128 fp16 = 25.6 MB
    int*      cnt   = (int*)(ws + 51200000);        // 400 KB
    int2*     epair = (int2*)(ws + 51600000);       // N*64*8 = 51.2 MB
    _Float16* wsT   = (_Float16*)(ws + 102800000);  // 64 KB
    _Float16* wdT   = (_Float16*)(ws + 102865536);  // 64 KB

    float* out0 = (float*)d_out;                // ft.mean: N*32 fp32
    float* out1 = out0 + N_NODES * DF;          // a.mean:  E fp32

    k_prep<<<128, 256, 0, stream>>>(w_src, w_dst, wsT, wdT, cnt);
    k_gemm<<<NB_G, 256, 0, stream>>>(x, wsT, wdT, b_src, b_dst, el, er);
    k_build<<<XCDS * BUILD_SLICES, 256, 0, stream>>>(src, dst, cnt, epair);
    k_node<<<N_NODES / 8, 256, 0, stream>>>(cnt, epair, el, er, attn, out0, out1);
}